// Round 8
// baseline (91.832 us; speedup 1.0000x reference)
//
#include <hip/hip_runtime.h>

#define N_NODES 100000
#define N_EDGES 1000000
#define D_FEAT  64

// Binning: 32 consecutive dst nodes per bin
#define BIN_SHIFT 5
#define BIN_NODES 32
#define NBINS ((N_NODES + BIN_NODES - 1) >> BIN_SHIFT)   // 3125 (exact: 3125*32=100000)
#define BIN_CAP 768    // mean edges/bin = 320, sigma ~18 -> 25 sigma headroom

// Deterministic partition: NB_PART contiguous edge chunks, radix-style.
#define NB_PART 256
#define CHUNK ((N_EDGES + NB_PART - 1) / NB_PART)        // 3907 (< 65536 -> u16 safe)

// ---------------------------------------------------------------------------
// Workspace layout:
//   H      [NBINS][NB_PART] u16   per-(bin,chunk) histogram -> excl offsets
//   T      [NBINS] int            per-bin totals
//   BASE   [NBINS] int            exclusive scan of T
//   bucket [N_EDGES] int          packed (local_dst << 17) | src, by bin
// total ~5.6 MB
// ---------------------------------------------------------------------------
#define WS_H_INTS ((NBINS * NB_PART + 1) / 2)
#define WS_T      WS_H_INTS
#define WS_BASE   (WS_T + NBINS)
#define WS_BUCKET (WS_BASE + NBINS)
#define WS_NEEDED ((size_t)(WS_BUCKET + N_EDGES) * sizeof(int))

// KA: per-chunk histogram (LDS privatized), 1024 threads, 256 blocks
__global__ __launch_bounds__(1024) void part_hist_kernel(const int* __restrict__ dst,
                                                         int* __restrict__ ws) {
    unsigned short* H = (unsigned short*)ws;
    __shared__ int h[NBINS];
    for (int j = threadIdx.x; j < NBINS; j += 1024) h[j] = 0;
    __syncthreads();
    int blk = blockIdx.x;
    int e0 = blk * CHUNK, e1 = min(N_EDGES, e0 + CHUNK);
    for (int e = e0 + threadIdx.x; e < e1; e += 1024)
        atomicAdd(&h[dst[e] >> BIN_SHIFT], 1);
    __syncthreads();
    for (int j = threadIdx.x; j < NBINS; j += 1024)
        H[j * NB_PART + blk] = (unsigned short)h[j];
}

// KB: per-bin exclusive scan across the 256 chunks (one wave per bin)
__global__ __launch_bounds__(256) void part_colscan_kernel(int* __restrict__ ws) {
    unsigned short* H = (unsigned short*)ws;
    int wave = threadIdx.x >> 6;
    int lane = threadIdx.x & 63;
    int j = blockIdx.x * 4 + wave;
    if (j >= NBINS) return;
    unsigned short* Hrow = H + j * NB_PART;

    int carry = 0;
    #pragma unroll
    for (int c = 0; c < NB_PART; c += 64) {
        int v = Hrow[c + lane];
        int incl = v;
        #pragma unroll
        for (int o = 1; o < 64; o <<= 1) {
            int t = __shfl_up(incl, o);
            if (lane >= o) incl += t;
        }
        Hrow[c + lane] = (unsigned short)(carry + incl - v);
        carry += __shfl(incl, 63);
    }
    if (lane == 63) ws[WS_T + j] = carry;
}

// KC: exclusive scan of bin totals -> BASE (LDS-staged serial wave)
__global__ __launch_bounds__(1024) void base_scan_kernel(int* __restrict__ ws) {
    const int PAD = ((NBINS + 63) / 64) * 64;
    __shared__ int sT[((NBINS + 63) / 64) * 64];
    for (int i = threadIdx.x; i < PAD; i += 1024)
        sT[i] = (i < NBINS) ? ws[WS_T + i] : 0;
    __syncthreads();
    if (threadIdx.x < 64) {
        int lane = threadIdx.x;
        int carry = 0;
        for (int c = 0; c < NBINS; c += 64) {
            int v = sT[c + lane];
            int incl = v;
            #pragma unroll
            for (int o = 1; o < 64; o <<= 1) {
                int t = __shfl_up(incl, o);
                if (lane >= o) incl += t;
            }
            if (c + lane < NBINS) ws[WS_BASE + c + lane] = carry + incl - v;
            carry += __shfl(incl, 63);
        }
    }
}

// KE: rank via LDS cursors (no global atomics), write packed edges into
// per-(chunk,bin) contiguous runs. 1024 threads, 256 blocks.
__global__ __launch_bounds__(1024) void part_scatter_kernel(const int* __restrict__ src,
                                                            const int* __restrict__ dst,
                                                            int* __restrict__ ws) {
    unsigned short* H = (unsigned short*)ws;
    __shared__ int cur[NBINS];
    int blk = blockIdx.x;
    for (int j = threadIdx.x; j < NBINS; j += 1024)
        cur[j] = ws[WS_BASE + j] + (int)H[j * NB_PART + blk];
    __syncthreads();
    int e0 = blk * CHUNK, e1 = min(N_EDGES, e0 + CHUNK);
    for (int e = e0 + threadIdx.x; e < e1; e += 1024) {
        int d = dst[e], s = src[e];
        int j = d >> BIN_SHIFT;
        int slot = atomicAdd(&cur[j], 1);          // LDS atomic
        ws[WS_BUCKET + slot] = ((d & (BIN_NODES - 1)) << 17) | s;
    }
}

// K5: per-bin counting-sort (LDS, bucket entries held in registers across the
// sync) + node-per-16-lane-group register gather. No cross-lane reduce:
// lane owns a float4 of the feature row; group serially accumulates its
// node's rows, unrolled x4 (4 rows in flight per group).
__global__ __launch_bounds__(256) void fused_gather_kernel(const float* __restrict__ emb,
                                                           const int* __restrict__ ws,
                                                           float* __restrict__ out) {
    __shared__ int s_sorted[BIN_CAP];
    __shared__ int s_hist[BIN_NODES];
    __shared__ int s_off[BIN_NODES];
    __shared__ int s_cur[BIN_NODES];

    int b   = blockIdx.x;
    int tid = threadIdx.x;
    int cnt  = ws[WS_T + b];
    if (cnt > BIN_CAP) cnt = BIN_CAP;   // statistically impossible; defensive
    int base = ws[WS_BASE + b];

    if (tid < BIN_NODES) s_hist[tid] = 0;
    __syncthreads();

    // load bucket entries into registers (<=3 per thread) + LDS histogram
    int p0 = 0, p1 = 0, p2 = 0;
    {
        const int* __restrict__ bucket = ws + WS_BUCKET + base;
        if (tid < cnt)       { p0 = bucket[tid];       atomicAdd(&s_hist[p0 >> 17], 1); }
        if (tid + 256 < cnt) { p1 = bucket[tid + 256]; atomicAdd(&s_hist[p1 >> 17], 1); }
        if (tid + 512 < cnt) { p2 = bucket[tid + 512]; atomicAdd(&s_hist[p2 >> 17], 1); }
    }
    __syncthreads();

    // scan 32 hist entries with the first 32 lanes
    if (tid < 32) {
        int v = s_hist[tid];
        int incl = v;
        #pragma unroll
        for (int o = 1; o < 32; o <<= 1) {
            int t = __shfl_up(incl, o);
            if (tid >= o) incl += t;
        }
        s_off[tid] = incl - v;
        s_cur[tid] = incl - v;
    }
    __syncthreads();

    // counting-sort scatter within LDS (store src only)
    if (tid < cnt)       s_sorted[atomicAdd(&s_cur[p0 >> 17], 1)] = p0 & 0x1FFFF;
    if (tid + 256 < cnt) s_sorted[atomicAdd(&s_cur[p1 >> 17], 1)] = p1 & 0x1FFFF;
    if (tid + 512 < cnt) s_sorted[atomicAdd(&s_cur[p2 >> 17], 1)] = p2 & 0x1FFFF;
    __syncthreads();

    // gather: 16 groups of 16 lanes; group = node, lane = float4 of the row
    int grp = tid >> 4;          // 0..15
    int fq  = tid & 15;          // float4 index

    #pragma unroll
    for (int rep = 0; rep < 2; ++rep) {
        int ln  = grp + rep * 16;      // 0..31
        int deg = s_hist[ln];
        int off = s_off[ln];

        float4 acc = make_float4(0.f, 0.f, 0.f, 0.f);
        int i = 0;
        for (; i + 4 <= deg; i += 4) {
            int s0 = s_sorted[off + i + 0];
            int s1 = s_sorted[off + i + 1];
            int s2 = s_sorted[off + i + 2];
            int s3 = s_sorted[off + i + 3];
            float4 v0 = ((const float4*)(emb + (size_t)s0 * D_FEAT))[fq];
            float4 v1 = ((const float4*)(emb + (size_t)s1 * D_FEAT))[fq];
            float4 v2 = ((const float4*)(emb + (size_t)s2 * D_FEAT))[fq];
            float4 v3 = ((const float4*)(emb + (size_t)s3 * D_FEAT))[fq];
            acc.x += v0.x + v1.x + v2.x + v3.x;
            acc.y += v0.y + v1.y + v2.y + v3.y;
            acc.z += v0.z + v1.z + v2.z + v3.z;
            acc.w += v0.w + v1.w + v2.w + v3.w;
        }
        for (; i < deg; ++i) {
            int s = s_sorted[off + i];
            float4 v = ((const float4*)(emb + (size_t)s * D_FEAT))[fq];
            acc.x += v.x; acc.y += v.y; acc.z += v.z; acc.w += v.w;
        }

        int node = (b << BIN_SHIFT) + ln;   // always < N_NODES (3125*32 exact)
        float inv = 1.0f / (float)max(deg, 1);
        acc.x *= inv; acc.y *= inv; acc.z *= inv; acc.w *= inv;
        *(float4*)(out + (size_t)node * D_FEAT + fq * 4) = acc;
    }
}

// ======================= Fallback (R1 atomic path) =========================

__global__ void gcn_zero_kernel(float* __restrict__ out, float* __restrict__ counts) {
    int stride = gridDim.x * blockDim.x;
    int i = blockIdx.x * blockDim.x + threadIdx.x;
    const int total = N_NODES * D_FEAT;
    for (int idx = i; idx < total; idx += stride) out[idx] = 0.0f;
    for (int idx = i; idx < N_NODES; idx += stride) counts[idx] = 0.0f;
}

__global__ void gcn_scatter_kernel(const float* __restrict__ emb,
                                   const int* __restrict__ src,
                                   const int* __restrict__ dst,
                                   float* __restrict__ out,
                                   float* __restrict__ counts) {
    int gid  = blockIdx.x * blockDim.x + threadIdx.x;
    int edge = gid >> 6;
    int lane = gid & 63;
    if (edge >= N_EDGES) return;
    int s = src[edge];
    int d = dst[edge];
    float v = emb[(size_t)s * D_FEAT + lane];
    atomicAdd(&out[(size_t)d * D_FEAT + lane], v);
    if (lane == 0) atomicAdd(&counts[d], 1.0f);
}

__global__ void gcn_norm_kernel(float* __restrict__ out,
                                const float* __restrict__ counts) {
    int i = blockIdx.x * blockDim.x + threadIdx.x;
    if (i >= N_NODES * D_FEAT) return;
    int n = i >> 6;
    float c = counts[n];
    out[i] *= (1.0f / fmaxf(c, 1.0f));
}

// ===========================================================================

extern "C" void kernel_launch(void* const* d_in, const int* in_sizes, int n_in,
                              void* d_out, int out_size, void* d_ws, size_t ws_size,
                              hipStream_t stream) {
    const float* emb = (const float*)d_in[0];
    const int*   src = (const int*)d_in[1];
    const int*   dst = (const int*)d_in[2];
    float* out = (float*)d_out;

    if (ws_size >= WS_NEEDED) {
        int* ws = (int*)d_ws;
        part_hist_kernel<<<NB_PART, 1024, 0, stream>>>(dst, ws);
        part_colscan_kernel<<<(NBINS + 3) / 4, 256, 0, stream>>>(ws);
        base_scan_kernel<<<1, 1024, 0, stream>>>(ws);
        part_scatter_kernel<<<NB_PART, 1024, 0, stream>>>(src, dst, ws);
        fused_gather_kernel<<<NBINS, 256, 0, stream>>>(emb, ws, out);
    } else {
        float* counts = (float*)d_ws;
        gcn_zero_kernel<<<2048, 256, 0, stream>>>(out, counts);
        const int scatter_blocks = (N_EDGES * 64) / 256;
        gcn_scatter_kernel<<<scatter_blocks, 256, 0, stream>>>(emb, src, dst, out, counts);
        const int norm_blocks = (N_NODES * D_FEAT + 255) / 256;
        gcn_norm_kernel<<<norm_blocks, 256, 0, stream>>>(out, counts);
    }
}